// Round 2
// baseline (4134.447 us; speedup 1.0000x reference)
//
#include <hip/hip_runtime.h>
#include <hip/hip_bf16.h>
#include <math.h>

typedef unsigned short u16;
typedef unsigned int   u32;

#define B_  2
#define T_  2048
#define C_  2048
#define H_  16
#define HD_ 128
#define M_  (B_ * T_)     // 4096 rows of x / qkv / y
#define N3C (3 * C_)      // 6144 qkv columns

// ---------- bf16 helpers ----------
__device__ __forceinline__ float bf2f_lo(u32 u) { return __uint_as_float(u << 16); }
__device__ __forceinline__ float bf2f_hi(u32 u) { return __uint_as_float(u & 0xffff0000u); }

__device__ __forceinline__ u16 f2bf(float f) {
    u32 u = __float_as_uint(f);
    return (u16)((u + 0x7fffu + ((u >> 16) & 1u)) >> 16);   // RNE
}

__device__ __forceinline__ void unpack8(uint4 v, float* d) {
    d[0] = bf2f_lo(v.x); d[1] = bf2f_hi(v.x);
    d[2] = bf2f_lo(v.y); d[3] = bf2f_hi(v.y);
    d[4] = bf2f_lo(v.z); d[5] = bf2f_hi(v.z);
    d[6] = bf2f_lo(v.w); d[7] = bf2f_hi(v.w);
}

// dtype-generic 8-element contiguous load -> fp32
__device__ __forceinline__ void load8f(const float* p, float* d) {
    float4 a = *(const float4*)p;
    float4 b = *(const float4*)(p + 4);
    d[0] = a.x; d[1] = a.y; d[2] = a.z; d[3] = a.w;
    d[4] = b.x; d[5] = b.y; d[6] = b.z; d[7] = b.w;
}
__device__ __forceinline__ void load8f(const __hip_bfloat16* p, float* d) {
    uint4 v = *(const uint4*)p;
    unpack8(v, d);
}
__device__ __forceinline__ void store1(float* p, float v) { *p = v; }
__device__ __forceinline__ void store1(__hip_bfloat16* p, float v) { *(u16*)p = f2bf(v); }

// ---------- GEMM (NT): C[m,n] = sum_k A[m,k] * W[n,k]; A:[M,K] W:[N,K], out TO ----------
// 64x64 tile, BK=32, 256 threads, each thread 4x4 outputs.
template <typename TA, typename TW, typename TO>
__global__ __launch_bounds__(256) void gemm_nt_64(const TA* __restrict__ A,
                                                  const TW* __restrict__ W,
                                                  TO* __restrict__ Cout,
                                                  int N, int K) {
    __shared__ float As[64][36];
    __shared__ float Bs[64][36];
    const int tid = threadIdx.x;
    const int bm = blockIdx.y * 64;
    const int bn = blockIdx.x * 64;
    const int ty = tid >> 4;          // 0..15
    const int tx = tid & 15;          // 0..15
    const int lrow = tid >> 2;        // 0..63
    const int lcol = (tid & 3) * 8;   // 0,8,16,24

    float acc[4][4];
#pragma unroll
    for (int r = 0; r < 4; ++r)
#pragma unroll
        for (int c = 0; c < 4; ++c) acc[r][c] = 0.f;

    for (int k0 = 0; k0 < K; k0 += 32) {
        float af[8], bf_[8];
        load8f(A + (size_t)(bm + lrow) * K + k0 + lcol, af);
        load8f(W + (size_t)(bn + lrow) * K + k0 + lcol, bf_);
        __syncthreads();   // previous iteration's readers done
        *(float4*)&As[lrow][lcol]     = make_float4(af[0], af[1], af[2], af[3]);
        *(float4*)&As[lrow][lcol + 4] = make_float4(af[4], af[5], af[6], af[7]);
        *(float4*)&Bs[lrow][lcol]     = make_float4(bf_[0], bf_[1], bf_[2], bf_[3]);
        *(float4*)&Bs[lrow][lcol + 4] = make_float4(bf_[4], bf_[5], bf_[6], bf_[7]);
        __syncthreads();

#pragma unroll
        for (int ks = 0; ks < 32; ks += 4) {
            float4 a4[4], b4[4];
#pragma unroll
            for (int r = 0; r < 4; ++r) a4[r] = *(const float4*)&As[ty * 4 + r][ks];
#pragma unroll
            for (int c = 0; c < 4; ++c) b4[c] = *(const float4*)&Bs[tx + 16 * c][ks];
#pragma unroll
            for (int r = 0; r < 4; ++r)
#pragma unroll
                for (int c = 0; c < 4; ++c) {
                    acc[r][c] = fmaf(a4[r].x, b4[c].x, acc[r][c]);
                    acc[r][c] = fmaf(a4[r].y, b4[c].y, acc[r][c]);
                    acc[r][c] = fmaf(a4[r].z, b4[c].z, acc[r][c]);
                    acc[r][c] = fmaf(a4[r].w, b4[c].w, acc[r][c]);
                }
        }
    }

#pragma unroll
    for (int r = 0; r < 4; ++r)
#pragma unroll
        for (int c = 0; c < 4; ++c)
            store1(Cout + (size_t)(bm + ty * 4 + r) * N + bn + tx + 16 * c, acc[r][c]);
}

// ---------- RoPE in-place on q,k thirds of qkv (bf16) ----------
__global__ __launch_bounds__(256) void rope_kernel(__hip_bfloat16* __restrict__ qkv) {
    const int id  = blockIdx.x * 256 + threadIdx.x;
    const int i   = id & 63;
    const int h   = (id >> 6) & (H_ - 1);
    const int qk  = (id >> 10) & 1;
    const int row = id >> 11;
    const int t   = row & (T_ - 1);
    const size_t base = (size_t)row * N3C + (size_t)qk * C_ + h * HD_ + 2 * i;
    u32* p = (u32*)((u16*)qkv + base);
    const u32 v = *p;
    const float x0 = bf2f_lo(v), x1 = bf2f_hi(v);
    const float l2th = 0.20762050593046f;               // log2(10000)/64
    const float theta = exp2f(-(float)i * l2th);
    const float ang = (float)t * theta;
    float s, c;
    sincosf(ang, &s, &c);
    const float o0 = x0 * c - x1 * s;
    const float o1 = x1 * c + x0 * s;
    *p = (u32)f2bf(o0) | ((u32)f2bf(o1) << 16);
}

// ---------- causal flash attention (bf16 qkv ws -> bf16 y ws) ----------
// grid: (T/32, B*H); block 256. Thread: row i = tid>>3, col-group jg = tid&7 (4 j's each),
// owns output dims dch = jg*16 .. +15. Online softmax; K-tiles of 32, causal skip.
__global__ __launch_bounds__(256) void attn_kernel(const __hip_bfloat16* __restrict__ qkv,
                                                   __hip_bfloat16* __restrict__ y) {
    __shared__ float Qs[32][132];
    __shared__ float Ks[32][132];
    __shared__ float Vs[32][132];
    const int tid = threadIdx.x;
    const int bh = blockIdx.y;
    const int b = bh >> 4, h = bh & 15;
    const int q0 = blockIdx.x * 32;
    const int i = tid >> 3;
    const int jg = tid & 7;
    const int dch = jg * 16;
    const size_t rowbase = (size_t)b * T_ * N3C + (size_t)h * HD_;

    // stage Q tile (32 x 128)
#pragma unroll
    for (int p = 0; p < 2; ++p) {
        const int oct = tid + p * 256;
        const int r = oct >> 4, c8 = (oct & 15) * 8;
        float f[8];
        load8f(qkv + rowbase + (size_t)(q0 + r) * N3C + c8, f);
        *(float4*)&Qs[r][c8]     = make_float4(f[0], f[1], f[2], f[3]);
        *(float4*)&Qs[r][c8 + 4] = make_float4(f[4], f[5], f[6], f[7]);
    }

    float m = -INFINITY, l = 0.f;
    float acc[16];
#pragma unroll
    for (int d = 0; d < 16; ++d) acc[d] = 0.f;

    const int ktiles = q0 / 32 + 1;
    for (int kt = 0; kt < ktiles; ++kt) {
        const int k0 = kt * 32;
        float kf[2][8], vf[2][8];
        int rr[2], cc[2];
#pragma unroll
        for (int p = 0; p < 2; ++p) {
            const int oct = tid + p * 256;
            rr[p] = oct >> 4;
            cc[p] = (oct & 15) * 8;
            const size_t gbase = rowbase + (size_t)(k0 + rr[p]) * N3C + cc[p];
            load8f(qkv + gbase + C_, kf[p]);
            load8f(qkv + gbase + 2 * C_, vf[p]);
        }
        __syncthreads();
#pragma unroll
        for (int p = 0; p < 2; ++p) {
            *(float4*)&Ks[rr[p]][cc[p]]     = make_float4(kf[p][0], kf[p][1], kf[p][2], kf[p][3]);
            *(float4*)&Ks[rr[p]][cc[p] + 4] = make_float4(kf[p][4], kf[p][5], kf[p][6], kf[p][7]);
            *(float4*)&Vs[rr[p]][cc[p]]     = make_float4(vf[p][0], vf[p][1], vf[p][2], vf[p][3]);
            *(float4*)&Vs[rr[p]][cc[p] + 4] = make_float4(vf[p][4], vf[p][5], vf[p][6], vf[p][7]);
        }
        __syncthreads();

        // scores: s[jj] = q_i . k_{jg*4+jj}
        float s4[4] = {0.f, 0.f, 0.f, 0.f};
#pragma unroll 8
        for (int ds = 0; ds < 128; ds += 4) {
            const float4 q4 = *(const float4*)&Qs[i][ds];
#pragma unroll
            for (int jj = 0; jj < 4; ++jj) {
                const float4 k4 = *(const float4*)&Ks[jg * 4 + jj][ds];
                s4[jj] = fmaf(q4.x, k4.x, s4[jj]);
                s4[jj] = fmaf(q4.y, k4.y, s4[jj]);
                s4[jj] = fmaf(q4.z, k4.z, s4[jj]);
                s4[jj] = fmaf(q4.w, k4.w, s4[jj]);
            }
        }

        const int qg = q0 + i;
        const float scale = 0.08838834764831845f;   // 1/sqrt(128)
        float tmax = -INFINITY;
#pragma unroll
        for (int jj = 0; jj < 4; ++jj) {
            const int kg = k0 + jg * 4 + jj;
            s4[jj] = (kg <= qg) ? s4[jj] * scale : -INFINITY;
            tmax = fmaxf(tmax, s4[jj]);
        }
        tmax = fmaxf(tmax, __shfl_xor(tmax, 1));
        tmax = fmaxf(tmax, __shfl_xor(tmax, 2));
        tmax = fmaxf(tmax, __shfl_xor(tmax, 4));

        const float mnew = fmaxf(m, tmax);          // finite from tile 0 on
        const float corr = expf(m - mnew);          // first tile: expf(-inf)=0
        float pj4[4];
        float psum = 0.f;
#pragma unroll
        for (int jj = 0; jj < 4; ++jj) {
            pj4[jj] = expf(s4[jj] - mnew);          // masked -> expf(-inf)=0
            psum += pj4[jj];
        }
        psum += __shfl_xor(psum, 1);
        psum += __shfl_xor(psum, 2);
        psum += __shfl_xor(psum, 4);
        l = l * corr + psum;
        m = mnew;
#pragma unroll
        for (int d = 0; d < 16; ++d) acc[d] *= corr;

        // PV: gather this row's 32 p's from the 8 lanes, accumulate dim-chunk
#pragma unroll
        for (int src = 0; src < 8; ++src) {
#pragma unroll
            for (int jj = 0; jj < 4; ++jj) {
                const float pv = __shfl(pj4[jj], src, 8);
                const int j = src * 4 + jj;
                const float4* vp = (const float4*)&Vs[j][dch];
#pragma unroll
                for (int q4i = 0; q4i < 4; ++q4i) {
                    const float4 vv = vp[q4i];
                    acc[q4i * 4 + 0] = fmaf(pv, vv.x, acc[q4i * 4 + 0]);
                    acc[q4i * 4 + 1] = fmaf(pv, vv.y, acc[q4i * 4 + 1]);
                    acc[q4i * 4 + 2] = fmaf(pv, vv.z, acc[q4i * 4 + 2]);
                    acc[q4i * 4 + 3] = fmaf(pv, vv.w, acc[q4i * 4 + 3]);
                }
            }
        }
    }

    const float inv = 1.0f / l;
    u32 ow[8];
#pragma unroll
    for (int e = 0; e < 8; ++e)
        ow[e] = (u32)f2bf(acc[2 * e] * inv) | ((u32)f2bf(acc[2 * e + 1] * inv) << 16);
    __hip_bfloat16* yp = y + (size_t)(b * T_ + q0 + i) * C_ + h * HD_ + dch;
    *(uint4*)yp       = make_uint4(ow[0], ow[1], ow[2], ow[3]);
    *((uint4*)yp + 1) = make_uint4(ow[4], ow[5], ow[6], ow[7]);
}

// ---------- launch ----------
extern "C" void kernel_launch(void* const* d_in, const int* in_sizes, int n_in,
                              void* d_out, int out_size, void* d_ws, size_t ws_size,
                              hipStream_t stream) {
    const float* x  = (const float*)d_in[0];          // [B,T,C] fp32
    // d_in[1] = causal mask, deduced analytically -> unused
    const float* Wa = (const float*)d_in[2];          // [3C,C] fp32
    const float* Wp = (const float*)d_in[3];          // [C,C] fp32
    float* out = (float*)d_out;                       // [B,T,C] fp32

    __hip_bfloat16* qkv = (__hip_bfloat16*)d_ws;                 // [4096, 6144] bf16 = 50.3 MB
    __hip_bfloat16* y   = qkv + (size_t)M_ * N3C;                // [4096, 2048] bf16 = 16.8 MB

    gemm_nt_64<float, float, __hip_bfloat16>
        <<<dim3(N3C / 64, M_ / 64), 256, 0, stream>>>(x, Wa, qkv, N3C, C_);
    rope_kernel<<<(M_ * C_) / 256, 256, 0, stream>>>(qkv);
    attn_kernel<<<dim3(T_ / 32, B_ * H_), 256, 0, stream>>>(qkv, y);
    gemm_nt_64<__hip_bfloat16, float, float>
        <<<dim3(C_ / 64, M_ / 64), 256, 0, stream>>>(y, Wp, out, C_, C_);
}

// Round 3
// 570.866 us; speedup vs baseline: 7.2424x; 7.2424x over previous
//
#include <hip/hip_runtime.h>
#include <hip/hip_bf16.h>
#include <math.h>

typedef unsigned short u16;
typedef unsigned int   u32;
typedef __attribute__((ext_vector_type(8))) short bf16x8;   // 8 bf16 (4 VGPRs)
typedef __attribute__((ext_vector_type(4))) float f32x4;

#define B_  2
#define T_  2048
#define C_  2048
#define H_  16
#define HD_ 128
#define M_  4096          // B*T
#define N3C 6144          // 3*C

// ---------- bf16 helpers ----------
__device__ __forceinline__ float bf2f_lo(u32 u) { return __uint_as_float(u << 16); }
__device__ __forceinline__ float bf2f_hi(u32 u) { return __uint_as_float(u & 0xffff0000u); }

__device__ __forceinline__ u16 f2bf(float f) {
    u32 u = __float_as_uint(f);
    return (u16)((u + 0x7fffu + ((u >> 16) & 1u)) >> 16);   // RNE
}
__device__ __forceinline__ u32 pack2(float a, float b) {
    return (u32)f2bf(a) | ((u32)f2bf(b) << 16);
}
__device__ __forceinline__ void store1(float* p, float v) { *p = v; }
__device__ __forceinline__ void store1(__hip_bfloat16* p, float v) { *(u16*)p = f2bf(v); }

// ---------- GEMM staging: 128x32 tile -> LDS bf16 pitch 40 ----------
__device__ __forceinline__ void stage_tile(u16* dst, const float* src, int ldk, int tid) {
    const int r0  = tid >> 3;         // 0..31
    const int off = (tid & 7) * 4;    // 0..28
#pragma unroll
    for (int it = 0; it < 4; ++it) {
        const int row = r0 + it * 32;
        const float4 v = *(const float4*)(src + (size_t)row * ldk + off);
        *(uint2*)&dst[row * 40 + off] = make_uint2(pack2(v.x, v.y), pack2(v.z, v.w));
    }
}
__device__ __forceinline__ void stage_tile(u16* dst, const __hip_bfloat16* src, int ldk, int tid) {
    const int r0  = tid >> 2;         // 0..63
    const int off = (tid & 3) * 8;    // 0..24
#pragma unroll
    for (int it = 0; it < 2; ++it) {
        const int row = r0 + it * 64;
        *(uint4*)&dst[row * 40 + off] = *(const uint4*)(src + (size_t)row * ldk + off);
    }
}

// ---------- MFMA GEMM (NT): C[m,n] = sum_k A[m,k]*W[n,k] ----------
// 128x128 tile, BK=32, 256 thr = 4 waves (2x2 of 64x64), 16 mfma_16x16x32/wave/K-step
template <typename TA, typename TW, typename TO>
__global__ __launch_bounds__(256) void gemm_mfma(const TA* __restrict__ A,
                                                 const TW* __restrict__ W,
                                                 TO* __restrict__ Cout,
                                                 int N, int K, int gx) {
    __shared__ u16 As[128 * 40];
    __shared__ u16 Bs[128 * 40];
    // XCD-bijective swizzle (grid counts are multiples of 8)
    const int nwg = gridDim.x * gridDim.y;
    const int id  = blockIdx.y * gx + blockIdx.x;
    const int swz = (id & 7) * (nwg >> 3) + (id >> 3);
    const int bm  = (swz / gx) * 128;
    const int bn  = (swz % gx) * 128;

    const int tid  = threadIdx.x;
    const int w    = tid >> 6;
    const int lane = tid & 63;
    const int g    = lane >> 4;       // 0..3
    const int c    = lane & 15;       // 0..15
    const int wr   = (w >> 1) * 64;
    const int wc   = (w & 1) * 64;

    f32x4 acc[4][4];
#pragma unroll
    for (int mi = 0; mi < 4; ++mi)
#pragma unroll
        for (int ni = 0; ni < 4; ++ni)
            acc[mi][ni] = (f32x4){0.f, 0.f, 0.f, 0.f};

    const TA* Ab = A + (size_t)bm * K;
    const TW* Wb = W + (size_t)bn * K;

    for (int k0 = 0; k0 < K; k0 += 32) {
        __syncthreads();              // protect previous iteration's frag reads
        stage_tile(As, Ab + k0, K, tid);
        stage_tile(Bs, Wb + k0, K, tid);
        __syncthreads();

        bf16x8 af[4], bfr[4];
#pragma unroll
        for (int mi = 0; mi < 4; ++mi)
            af[mi] = *(const bf16x8*)&As[(wr + mi * 16 + c) * 40 + g * 8];
#pragma unroll
        for (int ni = 0; ni < 4; ++ni)
            bfr[ni] = *(const bf16x8*)&Bs[(wc + ni * 16 + c) * 40 + g * 8];
#pragma unroll
        for (int mi = 0; mi < 4; ++mi)
#pragma unroll
            for (int ni = 0; ni < 4; ++ni)
                acc[mi][ni] = __builtin_amdgcn_mfma_f32_16x16x32_bf16(
                    af[mi], bfr[ni], acc[mi][ni], 0, 0, 0);
    }

    // C/D layout: col = lane&15, row = 4*(lane>>4) + i   [verified m89]
#pragma unroll
    for (int mi = 0; mi < 4; ++mi)
#pragma unroll
        for (int ni = 0; ni < 4; ++ni)
#pragma unroll
            for (int i = 0; i < 4; ++i) {
                const int row = bm + wr + mi * 16 + 4 * g + i;
                const int col = bn + wc + ni * 16 + c;
                store1(Cout + (size_t)row * N + col, acc[mi][ni][i]);
            }
}

// ---------- RoPE in-place on q,k thirds of qkv (bf16) ----------
__global__ __launch_bounds__(256) void rope_kernel(__hip_bfloat16* __restrict__ qkv) {
    const int id  = blockIdx.x * 256 + threadIdx.x;
    const int i   = id & 63;
    const int h   = (id >> 6) & (H_ - 1);
    const int qk  = (id >> 10) & 1;
    const int row = id >> 11;
    const int t   = row & (T_ - 1);
    const size_t base = (size_t)row * N3C + (size_t)qk * C_ + h * HD_ + 2 * i;
    u32* p = (u32*)((u16*)qkv + base);
    const u32 v = *p;
    const float x0 = bf2f_lo(v), x1 = bf2f_hi(v);
    const float l2th = 0.20762050593046f;               // log2(10000)/64
    const float theta = exp2f(-(float)i * l2th);
    const float ang = (float)t * theta;
    float s, cc;
    sincosf(ang, &s, &cc);
    *p = pack2(x0 * cc - x1 * s, x1 * cc + x0 * s);
}

// ---------- MFMA causal flash attention ----------
// grid (T/64, B*H), 256 thr = 4 waves; wave w owns q-rows q0+w*16..+15.
// K tiles of 64: K row-major LDS (pitch 136), V transposed LDS (pitch 72),
// P via per-wave LDS (pitch 72) to convert C-layout -> A-layout.
__global__ __launch_bounds__(256) void attn_mfma(const __hip_bfloat16* __restrict__ qkv,
                                                 __hip_bfloat16* __restrict__ y) {
    __shared__ u16 Ks[64 * 136];
    __shared__ u16 Vt[128 * 72];
    __shared__ u16 Ps[4 * 16 * 72];

    const int tid  = threadIdx.x;
    const int w    = tid >> 6;
    const int lane = tid & 63;
    const int g    = lane >> 4;
    const int c    = lane & 15;
    const int bhi  = blockIdx.y;
    const int b    = bhi >> 4, h = bhi & 15;
    const int qt   = blockIdx.x;
    const int q0   = qt * 64;

    const size_t base = (size_t)b * T_ * N3C + (size_t)h * HD_;
    const __hip_bfloat16* Qp = qkv + base;
    const __hip_bfloat16* Kp = qkv + base + C_;
    const __hip_bfloat16* Vp = qkv + base + 2 * C_;

    // Q fragments (A layout: row = lane&15, k = 32*kc + 8*g + j)
    bf16x8 qf[4];
    {
        const int qrow = q0 + w * 16 + c;
#pragma unroll
        for (int kc = 0; kc < 4; ++kc)
            qf[kc] = *(const bf16x8*)(Qp + (size_t)qrow * N3C + kc * 32 + g * 8);
    }

    f32x4 o[8];
#pragma unroll
    for (int db = 0; db < 8; ++db) o[db] = (f32x4){0.f, 0.f, 0.f, 0.f};
    float m_[4], l_[4];
#pragma unroll
    for (int i = 0; i < 4; ++i) { m_[i] = -1e30f; l_[i] = 0.f; }

    const int qout = q0 + w * 16 + 4 * g;   // output row for reg i is qout+i
    const float scale = 0.08838834764831845f;
    const int srow = tid >> 2;              // staging row 0..63
    const int scol = (tid & 3) * 32;        // staging col segment

    const int nkt = qt + 1;
    for (int kt = 0; kt < nkt; ++kt) {
        const int k0 = kt * 64;
        __syncthreads();                    // protect previous tile's LDS reads
#pragma unroll
        for (int it = 0; it < 4; ++it) {
            const int cs = scol + it * 8;
            const uint4 kv = *(const uint4*)(Kp + (size_t)(k0 + srow) * N3C + cs);
            *(uint4*)&Ks[srow * 136 + cs] = kv;
            const uint4 vv = *(const uint4*)(Vp + (size_t)(k0 + srow) * N3C + cs);
            const u32 vw[4] = {vv.x, vv.y, vv.z, vv.w};
#pragma unroll
            for (int j = 0; j < 8; ++j)
                Vt[(cs + j) * 72 + srow] = (u16)(vw[j >> 1] >> ((j & 1) * 16));
        }
        __syncthreads();

        // S = Q K^T : 4 col-frags of 16 keys, 4 K-chunks of 32 hd
        f32x4 s[4];
#pragma unroll
        for (int kb = 0; kb < 4; ++kb) {
            s[kb] = (f32x4){0.f, 0.f, 0.f, 0.f};
#pragma unroll
            for (int kc = 0; kc < 4; ++kc) {
                const bf16x8 kf = *(const bf16x8*)&Ks[(kb * 16 + c) * 136 + kc * 32 + g * 8];
                s[kb] = __builtin_amdgcn_mfma_f32_16x16x32_bf16(qf[kc], kf, s[kb], 0, 0, 0);
            }
        }

        // scale + causal mask (score row = qout+i, key = k0+kb*16+c)
#pragma unroll
        for (int kb = 0; kb < 4; ++kb) {
            const int key = k0 + kb * 16 + c;
#pragma unroll
            for (int i = 0; i < 4; ++i)
                s[kb][i] = (key <= qout + i) ? s[kb][i] * scale : -1e30f;
        }

        // row max across kb then across the 16 lanes of the group
        float mx[4];
#pragma unroll
        for (int i = 0; i < 4; ++i)
            mx[i] = fmaxf(fmaxf(s[0][i], s[1][i]), fmaxf(s[2][i], s[3][i]));
#pragma unroll
        for (int d = 1; d <= 8; d <<= 1)
#pragma unroll
            for (int i = 0; i < 4; ++i) mx[i] = fmaxf(mx[i], __shfl_xor(mx[i], d));

        float corr[4];
#pragma unroll
        for (int i = 0; i < 4; ++i) {
            const float mn = fmaxf(m_[i], mx[i]);
            corr[i] = expf(m_[i] - mn);
            m_[i] = mn;
        }

        // P = exp(S - m), write to per-wave LDS in bf16, accumulate row sums
        float ps[4] = {0.f, 0.f, 0.f, 0.f};
#pragma unroll
        for (int kb = 0; kb < 4; ++kb)
#pragma unroll
            for (int i = 0; i < 4; ++i) {
                const float p = expf(s[kb][i] - m_[i]);
                ps[i] += p;
                Ps[w * 1152 + (4 * g + i) * 72 + kb * 16 + c] = f2bf(p);
            }
#pragma unroll
        for (int d = 1; d <= 8; d <<= 1)
#pragma unroll
            for (int i = 0; i < 4; ++i) ps[i] += __shfl_xor(ps[i], d);
#pragma unroll
        for (int i = 0; i < 4; ++i) l_[i] = l_[i] * corr[i] + ps[i];
#pragma unroll
        for (int db = 0; db < 8; ++db)
#pragma unroll
            for (int i = 0; i < 4; ++i) o[db][i] *= corr[i];

        // O += P V  (A = P from LDS in A-layout; B = Vt rows contiguous)
#pragma unroll
        for (int kc2 = 0; kc2 < 2; ++kc2) {
            const bf16x8 pa = *(const bf16x8*)&Ps[w * 1152 + c * 72 + kc2 * 32 + g * 8];
#pragma unroll
            for (int db = 0; db < 8; ++db) {
                const bf16x8 vb = *(const bf16x8*)&Vt[(db * 16 + c) * 72 + kc2 * 32 + g * 8];
                o[db] = __builtin_amdgcn_mfma_f32_16x16x32_bf16(pa, vb, o[db], 0, 0, 0);
            }
        }
    }

    float inv[4];
#pragma unroll
    for (int i = 0; i < 4; ++i) inv[i] = 1.f / l_[i];
#pragma unroll
    for (int db = 0; db < 8; ++db)
#pragma unroll
        for (int i = 0; i < 4; ++i) {
            __hip_bfloat16* yp = y + (size_t)(b * T_ + qout + i) * C_ + h * HD_ + db * 16 + c;
            store1(yp, o[db][i] * inv[i]);
        }
}

// ---------- launch ----------
extern "C" void kernel_launch(void* const* d_in, const int* in_sizes, int n_in,
                              void* d_out, int out_size, void* d_ws, size_t ws_size,
                              hipStream_t stream) {
    const float* x  = (const float*)d_in[0];          // [B,T,C] fp32
    // d_in[1] = causal mask (analytic) -> unused
    const float* Wa = (const float*)d_in[2];          // [3C,C] fp32
    const float* Wp = (const float*)d_in[3];          // [C,C] fp32
    float* out = (float*)d_out;                       // [B,T,C] fp32

    __hip_bfloat16* qkv = (__hip_bfloat16*)d_ws;                 // [4096,6144] bf16
    __hip_bfloat16* y   = qkv + (size_t)M_ * N3C;                // [4096,2048] bf16

    gemm_mfma<float, float, __hip_bfloat16>
        <<<dim3(N3C / 128, M_ / 128), 256, 0, stream>>>(x, Wa, qkv, N3C, C_, N3C / 128);
    rope_kernel<<<(M_ * C_) / 256, 256, 0, stream>>>(qkv);
    attn_mfma<<<dim3(T_ / 64, B_ * H_), 256, 0, stream>>>(qkv, y);
    gemm_mfma<__hip_bfloat16, float, float>
        <<<dim3(C_ / 128, M_ / 128), 256, 0, stream>>>(y, Wp, out, C_, C_, C_ / 128);
}

// Round 4
// 401.332 us; speedup vs baseline: 10.3018x; 1.4224x over previous
//
#include <hip/hip_runtime.h>
#include <hip/hip_bf16.h>
#include <math.h>

typedef unsigned short u16;
typedef unsigned int   u32;
typedef __attribute__((ext_vector_type(8)))  short bf16x8;   // 8 bf16 (4 VGPRs)
typedef __attribute__((ext_vector_type(4)))  float f32x4;
typedef __attribute__((ext_vector_type(16))) float f32x16;

#define B_  2
#define T_  2048
#define C_  2048
#define H_  16
#define HD_ 128
#define M_  4096          // B*T
#define N3C 6144          // 3*C

// ---------- bf16 helpers ----------
__device__ __forceinline__ float bf2f_lo(u32 u) { return __uint_as_float(u << 16); }
__device__ __forceinline__ float bf2f_hi(u32 u) { return __uint_as_float(u & 0xffff0000u); }

__device__ __forceinline__ u16 f2bf(float f) {
    u32 u = __float_as_uint(f);
    return (u16)((u + 0x7fffu + ((u >> 16) & 1u)) >> 16);   // RNE
}
__device__ __forceinline__ u32 pack2(float a, float b) {
    return (u32)f2bf(a) | ((u32)f2bf(b) << 16);
}
__device__ __forceinline__ void store1(float* p, float v) { *p = v; }
__device__ __forceinline__ void store1(__hip_bfloat16* p, float v) { *(u16*)p = f2bf(v); }

// ---------- GEMM staging: 128x32 tile -> LDS bf16 pitch 40 ----------
__device__ __forceinline__ void stage_tile(u16* dst, const float* src, int ldk, int tid) {
    const int r0  = tid >> 3;         // 0..31
    const int off = (tid & 7) * 4;    // 0..28
#pragma unroll
    for (int it = 0; it < 4; ++it) {
        const int row = r0 + it * 32;
        const float4 v = *(const float4*)(src + (size_t)row * ldk + off);
        *(uint2*)&dst[row * 40 + off] = make_uint2(pack2(v.x, v.y), pack2(v.z, v.w));
    }
}
__device__ __forceinline__ void stage_tile(u16* dst, const __hip_bfloat16* src, int ldk, int tid) {
    const int r0  = tid >> 2;         // 0..63
    const int off = (tid & 3) * 8;    // 0..24
#pragma unroll
    for (int it = 0; it < 2; ++it) {
        const int row = r0 + it * 64;
        *(uint4*)&dst[row * 40 + off] = *(const uint4*)(src + (size_t)row * ldk + off);
    }
}

// ---------- MFMA GEMM (NT): C[m,n] = sum_k A[m,k]*W[n,k] ----------
// 128x128 tile, BK=32, 256 thr = 4 waves (2x2 of 64x64), 16 mfma_16x16x32/wave/K-step
template <typename TA, typename TW, typename TO>
__global__ __launch_bounds__(256) void gemm_mfma(const TA* __restrict__ A,
                                                 const TW* __restrict__ W,
                                                 TO* __restrict__ Cout,
                                                 int N, int K, int gx) {
    __shared__ u16 As[128 * 40];
    __shared__ u16 Bs[128 * 40];
    const int nwg = gridDim.x * gridDim.y;
    const int id  = blockIdx.y * gx + blockIdx.x;
    const int swz = (id & 7) * (nwg >> 3) + (id >> 3);
    const int bm  = (swz / gx) * 128;
    const int bn  = (swz % gx) * 128;

    const int tid  = threadIdx.x;
    const int w    = tid >> 6;
    const int lane = tid & 63;
    const int g    = lane >> 4;       // 0..3
    const int c    = lane & 15;       // 0..15
    const int wr   = (w >> 1) * 64;
    const int wc   = (w & 1) * 64;

    f32x4 acc[4][4];
#pragma unroll
    for (int mi = 0; mi < 4; ++mi)
#pragma unroll
        for (int ni = 0; ni < 4; ++ni)
            acc[mi][ni] = (f32x4){0.f, 0.f, 0.f, 0.f};

    const TA* Ab = A + (size_t)bm * K;
    const TW* Wb = W + (size_t)bn * K;

    for (int k0 = 0; k0 < K; k0 += 32) {
        __syncthreads();
        stage_tile(As, Ab + k0, K, tid);
        stage_tile(Bs, Wb + k0, K, tid);
        __syncthreads();

        bf16x8 af[4], bfr[4];
#pragma unroll
        for (int mi = 0; mi < 4; ++mi)
            af[mi] = *(const bf16x8*)&As[(wr + mi * 16 + c) * 40 + g * 8];
#pragma unroll
        for (int ni = 0; ni < 4; ++ni)
            bfr[ni] = *(const bf16x8*)&Bs[(wc + ni * 16 + c) * 40 + g * 8];
#pragma unroll
        for (int mi = 0; mi < 4; ++mi)
#pragma unroll
            for (int ni = 0; ni < 4; ++ni)
                acc[mi][ni] = __builtin_amdgcn_mfma_f32_16x16x32_bf16(
                    af[mi], bfr[ni], acc[mi][ni], 0, 0, 0);
    }

#pragma unroll
    for (int mi = 0; mi < 4; ++mi)
#pragma unroll
        for (int ni = 0; ni < 4; ++ni)
#pragma unroll
            for (int i = 0; i < 4; ++i) {
                const int row = bm + wr + mi * 16 + 4 * g + i;
                const int col = bn + wc + ni * 16 + c;
                store1(Cout + (size_t)row * N + col, acc[mi][ni][i]);
            }
}

// ---------- RoPE in-place on q,k thirds of qkv (bf16) ----------
__global__ __launch_bounds__(256) void rope_kernel(__hip_bfloat16* __restrict__ qkv) {
    const int id  = blockIdx.x * 256 + threadIdx.x;
    const int i   = id & 63;
    const int h   = (id >> 6) & (H_ - 1);
    const int qk  = (id >> 10) & 1;
    const int row = id >> 11;
    const int t   = row & (T_ - 1);
    const size_t base = (size_t)row * N3C + (size_t)qk * C_ + h * HD_ + 2 * i;
    u32* p = (u32*)((u16*)qkv + base);
    const u32 v = *p;
    const float x0 = bf2f_lo(v), x1 = bf2f_hi(v);
    const float l2th = 0.20762050593046f;               // log2(10000)/64
    const float theta = exp2f(-(float)i * l2th);
    const float ang = (float)t * theta;
    float s, cc;
    sincosf(ang, &s, &cc);
    *p = pack2(x0 * cc - x1 * s, x1 * cc + x0 * s);
}

// ---------- MFMA causal flash attention, 32x32 swapped-QK ----------
// grid 512 linear: bh = bid&31 (XCD = bh&7), qb = 15 - (bid>>5) (long blocks first).
// Block: 4 waves, wave w owns q-rows [qb*128 + 32w, +32). K-tile = 64 keys.
// S^T = mfma32x32(K, Q): lane holds P[q = lane&31][16 keys]; softmax lane-local.
// PV: A-frag = packed own p-regs (sigma-permuted k-slots); B-frag = Vt b128 reads.
// Vt columns: pi(key) = swap bits2,3, XOR'd by (d>>5)<<4 (conflict-free writes).
__device__ __forceinline__ int PI_(int s) {
    return (s & 51) | ((s & 4) << 1) | ((s & 8) >> 1);
}

__global__ __launch_bounds__(256, 2) void attn_mfma2(const __hip_bfloat16* __restrict__ qkv,
                                                     __hip_bfloat16* __restrict__ y) {
    __shared__ u16 Ks[64 * 136];
    __shared__ u16 Vt[128 * 72];
    __shared__ float Red[128];

    const int tid  = threadIdx.x;
    const int w    = tid >> 6;
    const int lane = tid & 63;
    const int c31  = lane & 31;
    const int hi   = lane >> 5;
    const int bid  = blockIdx.x;
    const int bh   = bid & 31;
    const int qb   = 15 - (bid >> 5);
    const int b    = bh >> 4, h = bh & 15;
    const int q0   = qb * 128;

    const size_t base = (size_t)b * T_ * N3C + (size_t)h * HD_;
    const __hip_bfloat16* Qp = qkv + base;
    const __hip_bfloat16* Kp = qkv + base + C_;
    const __hip_bfloat16* Vp = qkv + base + 2 * C_;

    // Q fragments: B-operand slots (hi,j) = Q[qrow][16kc + 8hi + j]
    bf16x8 qf[8];
    {
        const size_t qoff = (size_t)(q0 + w * 32 + c31) * N3C + hi * 8;
#pragma unroll
        for (int kc = 0; kc < 8; ++kc)
            qf[kc] = *(const bf16x8*)(Qp + qoff + kc * 16);
    }

    f32x16 o[4];
#pragma unroll
    for (int db = 0; db < 4; ++db)
#pragma unroll
        for (int r = 0; r < 16; ++r) o[db][r] = 0.f;

    float m_ = -1e30f, l_ = 0.f;
    const int   myq   = q0 + w * 32 + c31;
    const float SCALE = 0.08838834764831845f;   // 1/sqrt(128)

    const int s_   = tid >> 2;        // staged key row 0..63
    const int dsub = tid & 3;         // 32-col segment
    const int vcol = PI_(s_) ^ (dsub << 4);

    const int nkt = 2 * qb + 2;
    for (int kt = 0; kt < nkt; ++kt) {
        const int k0 = kt * 64;
        __syncthreads();              // protect previous tile's LDS reads
#pragma unroll
        for (int it = 0; it < 4; ++it) {
            const int col = dsub * 32 + it * 8;
            const size_t goff = (size_t)(k0 + s_) * N3C + col;
            *(uint4*)&Ks[s_ * 136 + col] = *(const uint4*)(Kp + goff);
            const uint4 vv = *(const uint4*)(Vp + goff);
            const u32 vw[4] = {vv.x, vv.y, vv.z, vv.w};
#pragma unroll
            for (int j = 0; j < 8; ++j)
                Vt[(col + j) * 72 + vcol] = (u16)(vw[j >> 1] >> ((j & 1) * 16));
        }
        __syncthreads();

        // S^T chunks: keys [k0,k0+32) and [k0+32,k0+64)
        f32x16 sA, sB;
#pragma unroll
        for (int r = 0; r < 16; ++r) { sA[r] = 0.f; sB[r] = 0.f; }
#pragma unroll
        for (int kc = 0; kc < 8; ++kc) {
            const bf16x8 ka = *(const bf16x8*)&Ks[c31 * 136 + kc * 16 + hi * 8];
            sA = __builtin_amdgcn_mfma_f32_32x32x16_bf16(ka, qf[kc], sA, 0, 0, 0);
            const bf16x8 kb_ = *(const bf16x8*)&Ks[(32 + c31) * 136 + kc * 16 + hi * 8];
            sB = __builtin_amdgcn_mfma_f32_32x32x16_bf16(kb_, qf[kc], sB, 0, 0, 0);
        }

        // scale + causal mask; reg r holds key_local = (r&3) + 8*(r>>2) + 4*hi
        float pmax = -1e30f;
#pragma unroll
        for (int r = 0; r < 16; ++r) {
            const int cr = (r & 3) + 8 * (r >> 2) + 4 * hi;
            sA[r] = (k0 + cr      <= myq) ? sA[r] * SCALE : -1e30f;
            sB[r] = (k0 + 32 + cr <= myq) ? sB[r] * SCALE : -1e30f;
            pmax = fmaxf(pmax, fmaxf(sA[r], sB[r]));
        }
        pmax = fmaxf(pmax, __shfl_xor(pmax, 32));

        // defer-max (T13): rescale only when a row's max grew by > 8
        if (__any(pmax > m_ + 8.f)) {
            const float mn   = fmaxf(m_, pmax);
            const float corr = __expf(m_ - mn);
            Red[w * 32 + c31] = corr;                 // lane-space -> reg-space bounce
            float cf[16];
#pragma unroll
            for (int r = 0; r < 16; ++r)
                cf[r] = Red[w * 32 + ((r & 3) + 8 * (r >> 2) + 4 * hi)];
#pragma unroll
            for (int db = 0; db < 4; ++db)
#pragma unroll
                for (int r = 0; r < 16; ++r) o[db][r] *= cf[r];
            l_ *= corr;
            m_ = mn;
        }

        float psum = 0.f;
#pragma unroll
        for (int r = 0; r < 16; ++r) {
            sA[r] = __expf(sA[r] - m_); psum += sA[r];
            sB[r] = __expf(sB[r] - m_); psum += sB[r];
        }
        psum += __shfl_xor(psum, 32);
        l_ += psum;

        // O += P V : A-frag for chunk kb2, k-half c2 = packed regs [8c2..8c2+7]
#pragma unroll
        for (int kb2 = 0; kb2 < 2; ++kb2) {
#pragma unroll
            for (int c2 = 0; c2 < 2; ++c2) {
                union { u32 u[4]; bf16x8 v; } pk;
#pragma unroll
                for (int q2 = 0; q2 < 4; ++q2) {
                    const int r = 8 * c2 + 2 * q2;
                    const float e0 = kb2 ? sB[r]     : sA[r];
                    const float e1 = kb2 ? sB[r + 1] : sA[r + 1];
                    pk.u[q2] = pack2(e0, e1);
                }
#pragma unroll
                for (int db = 0; db < 4; ++db) {
                    const int colb = (kb2 * 32 + c2 * 16 + hi * 8) ^ (db << 4);
                    const bf16x8 vb = *(const bf16x8*)&Vt[(db * 32 + c31) * 72 + colb];
                    o[db] = __builtin_amdgcn_mfma_f32_32x32x16_bf16(pk.v, vb, o[db], 0, 0, 0);
                }
            }
        }
    }

    // epilogue: bounce l to reg-space, normalize, store
    Red[w * 32 + c31] = l_;
    float lv[16];
#pragma unroll
    for (int r = 0; r < 16; ++r)
        lv[r] = 1.f / Red[w * 32 + ((r & 3) + 8 * (r >> 2) + 4 * hi)];
#pragma unroll
    for (int db = 0; db < 4; ++db)
#pragma unroll
        for (int r = 0; r < 16; ++r) {
            const int q = q0 + w * 32 + (r & 3) + 8 * (r >> 2) + 4 * hi;
            store1(y + (size_t)(b * T_ + q) * C_ + h * HD_ + db * 32 + c31,
                   o[db][r] * lv[r]);
        }
}

// ---------- launch ----------
extern "C" void kernel_launch(void* const* d_in, const int* in_sizes, int n_in,
                              void* d_out, int out_size, void* d_ws, size_t ws_size,
                              hipStream_t stream) {
    const float* x  = (const float*)d_in[0];          // [B,T,C] fp32
    // d_in[1] = causal mask (analytic) -> unused
    const float* Wa = (const float*)d_in[2];          // [3C,C] fp32
    const float* Wp = (const float*)d_in[3];          // [C,C] fp32
    float* out = (float*)d_out;                       // [B,T,C] fp32

    __hip_bfloat16* qkv = (__hip_bfloat16*)d_ws;                 // [4096,6144] bf16
    __hip_bfloat16* y   = qkv + (size_t)M_ * N3C;                // [4096,2048] bf16

    gemm_mfma<float, float, __hip_bfloat16>
        <<<dim3(N3C / 128, M_ / 128), 256, 0, stream>>>(x, Wa, qkv, N3C, C_, N3C / 128);
    rope_kernel<<<(M_ * C_) / 256, 256, 0, stream>>>(qkv);
    attn_mfma2<<<512, 256, 0, stream>>>(qkv, y);
    gemm_mfma<__hip_bfloat16, float, float>
        <<<dim3(C_ / 128, M_ / 128), 256, 0, stream>>>(y, Wp, out, C_, C_, C_ / 128);
}

// Round 5
// 322.992 us; speedup vs baseline: 12.8005x; 1.2425x over previous
//
#include <hip/hip_runtime.h>
#include <hip/hip_bf16.h>
#include <math.h>

typedef unsigned short u16;
typedef unsigned int   u32;
typedef __attribute__((ext_vector_type(8)))  short bf16x8;   // 8 bf16 (4 VGPRs)
typedef __attribute__((ext_vector_type(4)))  float f32x4;
typedef __attribute__((ext_vector_type(16))) float f32x16;

#define B_  2
#define T_  2048
#define C_  2048
#define H_  16
#define HD_ 128
#define M_  4096          // B*T
#define N3C 6144          // 3*C

// ---------- bf16 helpers ----------
__device__ __forceinline__ float bf2f_lo(u32 u) { return __uint_as_float(u << 16); }
__device__ __forceinline__ float bf2f_hi(u32 u) { return __uint_as_float(u & 0xffff0000u); }

__device__ __forceinline__ u16 f2bf(float f) {
    u32 u = __float_as_uint(f);
    return (u16)((u + 0x7fffu + ((u >> 16) & 1u)) >> 16);   // RNE
}
__device__ __forceinline__ u32 pack2(float a, float b) {
    return (u32)f2bf(a) | ((u32)f2bf(b) << 16);
}
__device__ __forceinline__ void store1(float* p, float v) { *p = v; }
__device__ __forceinline__ void store1(__hip_bfloat16* p, float v) { *(u16*)p = f2bf(v); }

// async global->LDS, 16B per lane (wave-uniform LDS base + lane*16)
__device__ __forceinline__ void gload16(const void* g, void* l) {
    __builtin_amdgcn_global_load_lds((__attribute__((address_space(1))) void*)g,
                                     (__attribute__((address_space(3))) void*)l, 16, 0, 0);
}

// ---------- fp32 -> bf16 convert (memory-bound, 8 elems/thread) ----------
__global__ __launch_bounds__(256) void cvt_bf16(const float* __restrict__ in,
                                                u16* __restrict__ out, int n8) {
    const int i = blockIdx.x * 256 + threadIdx.x;
    if (i < n8) {
        const float4 a = ((const float4*)in)[2 * i];
        const float4 b = ((const float4*)in)[2 * i + 1];
        ((uint4*)out)[i] = make_uint4(pack2(a.x, a.y), pack2(a.z, a.w),
                                      pack2(b.x, b.y), pack2(b.z, b.w));
    }
}

// ---------- m97-structure bf16 GEMM (NT): C[m,n] = sum_k A[m,k]*W[n,k] ----------
// 128x128 tile, BK=32, 4 waves; linear LDS [128][32]; global_load_lds staging.
template <typename TO>
__global__ __launch_bounds__(256) void gemm_lds(const __hip_bfloat16* __restrict__ A,
                                                const __hip_bfloat16* __restrict__ W,
                                                TO* __restrict__ Cout,
                                                int N, int K, int gx) {
    __shared__ u16 As[128 * 32];
    __shared__ u16 Bs[128 * 32];
    const int nwg = gridDim.x * gridDim.y;
    const int id  = blockIdx.y * gx + blockIdx.x;
    const int swz = (id & 7) * (nwg >> 3) + (id >> 3);
    const int bm  = (swz / gx) * 128;
    const int bn  = (swz % gx) * 128;

    const int tid  = threadIdx.x;
    const int w    = tid >> 6;
    const int lane = tid & 63;
    const int g    = lane >> 4;       // 0..3
    const int c    = lane & 15;       // 0..15
    const int wr   = (w >> 1) * 64;
    const int wc   = (w & 1) * 64;

    // staging: wave w covers rows [w*32, w*32+32) of the 128-row tile,
    // two 16-row instructions each for A and B; lane l -> row +l/4, col (l&3)*8
    const int srow = lane >> 2;
    const int scol = (lane & 3) * 8;
    const __hip_bfloat16* ga0 = A + (size_t)(bm + w * 32 + srow) * K + scol;
    const __hip_bfloat16* ga1 = ga0 + (size_t)16 * K;
    const __hip_bfloat16* gb0 = W + (size_t)(bn + w * 32 + srow) * K + scol;
    const __hip_bfloat16* gb1 = gb0 + (size_t)16 * K;
    u16* la0 = &As[(w * 32) * 32];
    u16* la1 = &As[(w * 32 + 16) * 32];
    u16* lb0 = &Bs[(w * 32) * 32];
    u16* lb1 = &Bs[(w * 32 + 16) * 32];

    f32x4 acc[4][4];
#pragma unroll
    for (int mi = 0; mi < 4; ++mi)
#pragma unroll
        for (int ni = 0; ni < 4; ++ni)
            acc[mi][ni] = (f32x4){0.f, 0.f, 0.f, 0.f};

    for (int k0 = 0; k0 < K; k0 += 32) {
        __syncthreads();              // previous iteration's frag reads done
        gload16(ga0 + k0, la0);
        gload16(ga1 + k0, la1);
        gload16(gb0 + k0, lb0);
        gload16(gb1 + k0, lb1);
        __syncthreads();              // drains vmcnt -> tile visible

        bf16x8 af[4], bfr[4];
#pragma unroll
        for (int mi = 0; mi < 4; ++mi)
            af[mi] = *(const bf16x8*)&As[(wr + mi * 16 + c) * 32 + g * 8];
#pragma unroll
        for (int ni = 0; ni < 4; ++ni)
            bfr[ni] = *(const bf16x8*)&Bs[(wc + ni * 16 + c) * 32 + g * 8];
#pragma unroll
        for (int mi = 0; mi < 4; ++mi)
#pragma unroll
            for (int ni = 0; ni < 4; ++ni)
                acc[mi][ni] = __builtin_amdgcn_mfma_f32_16x16x32_bf16(
                    af[mi], bfr[ni], acc[mi][ni], 0, 0, 0);
    }

    // C/D layout: col = lane&15, row = 4*(lane>>4) + i   [verified m89]
#pragma unroll
    for (int mi = 0; mi < 4; ++mi)
#pragma unroll
        for (int ni = 0; ni < 4; ++ni)
#pragma unroll
            for (int i = 0; i < 4; ++i) {
                const int row = bm + wr + mi * 16 + 4 * g + i;
                const int col = bn + wc + ni * 16 + c;
                store1(Cout + (size_t)row * N + col, acc[mi][ni][i]);
            }
}

// ---------- fallback reg-staged GEMM (fp32 or bf16 sources) ----------
__device__ __forceinline__ void stage_tile(u16* dst, const float* src, int ldk, int tid) {
    const int r0  = tid >> 3;
    const int off = (tid & 7) * 4;
#pragma unroll
    for (int it = 0; it < 4; ++it) {
        const int row = r0 + it * 32;
        const float4 v = *(const float4*)(src + (size_t)row * ldk + off);
        *(uint2*)&dst[row * 40 + off] = make_uint2(pack2(v.x, v.y), pack2(v.z, v.w));
    }
}
__device__ __forceinline__ void stage_tile(u16* dst, const __hip_bfloat16* src, int ldk, int tid) {
    const int r0  = tid >> 2;
    const int off = (tid & 3) * 8;
#pragma unroll
    for (int it = 0; it < 2; ++it) {
        const int row = r0 + it * 64;
        *(uint4*)&dst[row * 40 + off] = *(const uint4*)(src + (size_t)row * ldk + off);
    }
}

template <typename TA, typename TW, typename TO>
__global__ __launch_bounds__(256) void gemm_mfma(const TA* __restrict__ A,
                                                 const TW* __restrict__ W,
                                                 TO* __restrict__ Cout,
                                                 int N, int K, int gx) {
    __shared__ u16 As[128 * 40];
    __shared__ u16 Bs[128 * 40];
    const int nwg = gridDim.x * gridDim.y;
    const int id  = blockIdx.y * gx + blockIdx.x;
    const int swz = (id & 7) * (nwg >> 3) + (id >> 3);
    const int bm  = (swz / gx) * 128;
    const int bn  = (swz % gx) * 128;

    const int tid  = threadIdx.x;
    const int w    = tid >> 6;
    const int lane = tid & 63;
    const int g    = lane >> 4;
    const int c    = lane & 15;
    const int wr   = (w >> 1) * 64;
    const int wc   = (w & 1) * 64;

    f32x4 acc[4][4];
#pragma unroll
    for (int mi = 0; mi < 4; ++mi)
#pragma unroll
        for (int ni = 0; ni < 4; ++ni)
            acc[mi][ni] = (f32x4){0.f, 0.f, 0.f, 0.f};

    const TA* Ab = A + (size_t)bm * K;
    const TW* Wb = W + (size_t)bn * K;

    for (int k0 = 0; k0 < K; k0 += 32) {
        __syncthreads();
        stage_tile(As, Ab + k0, K, tid);
        stage_tile(Bs, Wb + k0, K, tid);
        __syncthreads();

        bf16x8 af[4], bfr[4];
#pragma unroll
        for (int mi = 0; mi < 4; ++mi)
            af[mi] = *(const bf16x8*)&As[(wr + mi * 16 + c) * 40 + g * 8];
#pragma unroll
        for (int ni = 0; ni < 4; ++ni)
            bfr[ni] = *(const bf16x8*)&Bs[(wc + ni * 16 + c) * 40 + g * 8];
#pragma unroll
        for (int mi = 0; mi < 4; ++mi)
#pragma unroll
            for (int ni = 0; ni < 4; ++ni)
                acc[mi][ni] = __builtin_amdgcn_mfma_f32_16x16x32_bf16(
                    af[mi], bfr[ni], acc[mi][ni], 0, 0, 0);
    }

#pragma unroll
    for (int mi = 0; mi < 4; ++mi)
#pragma unroll
        for (int ni = 0; ni < 4; ++ni)
#pragma unroll
            for (int i = 0; i < 4; ++i) {
                const int row = bm + wr + mi * 16 + 4 * g + i;
                const int col = bn + wc + ni * 16 + c;
                store1(Cout + (size_t)row * N + col, acc[mi][ni][i]);
            }
}

// ---------- RoPE in-place on q,k thirds of qkv (bf16) ----------
__global__ __launch_bounds__(256) void rope_kernel(__hip_bfloat16* __restrict__ qkv) {
    const int id  = blockIdx.x * 256 + threadIdx.x;
    const int i   = id & 63;
    const int h   = (id >> 6) & (H_ - 1);
    const int qk  = (id >> 10) & 1;
    const int row = id >> 11;
    const int t   = row & (T_ - 1);
    const size_t base = (size_t)row * N3C + (size_t)qk * C_ + h * HD_ + 2 * i;
    u32* p = (u32*)((u16*)qkv + base);
    const u32 v = *p;
    const float x0 = bf2f_lo(v), x1 = bf2f_hi(v);
    const float l2th = 0.20762050593046f;               // log2(10000)/64
    const float theta = exp2f(-(float)i * l2th);
    const float ang = (float)t * theta;
    float s, cc;
    sincosf(ang, &s, &cc);
    *p = pack2(x0 * cc - x1 * s, x1 * cc + x0 * s);
}

// ---------- MFMA causal flash attention, 32x32 swapped-QK ----------
__device__ __forceinline__ int PI_(int s) {
    return (s & 51) | ((s & 4) << 1) | ((s & 8) >> 1);
}

__global__ __launch_bounds__(256, 2) void attn_mfma2(const __hip_bfloat16* __restrict__ qkv,
                                                     __hip_bfloat16* __restrict__ y) {
    __shared__ u16 Ks[64 * 136];
    __shared__ u16 Vt[128 * 72];
    __shared__ float Red[128];

    const int tid  = threadIdx.x;
    const int w    = tid >> 6;
    const int lane = tid & 63;
    const int c31  = lane & 31;
    const int hi   = lane >> 5;
    const int bid  = blockIdx.x;
    const int bh   = bid & 31;
    const int qb   = 15 - (bid >> 5);
    const int b    = bh >> 4, h = bh & 15;
    const int q0   = qb * 128;

    const size_t base = (size_t)b * T_ * N3C + (size_t)h * HD_;
    const __hip_bfloat16* Qp = qkv + base;
    const __hip_bfloat16* Kp = qkv + base + C_;
    const __hip_bfloat16* Vp = qkv + base + 2 * C_;

    bf16x8 qf[8];
    {
        const size_t qoff = (size_t)(q0 + w * 32 + c31) * N3C + hi * 8;
#pragma unroll
        for (int kc = 0; kc < 8; ++kc)
            qf[kc] = *(const bf16x8*)(Qp + qoff + kc * 16);
    }

    f32x16 o[4];
#pragma unroll
    for (int db = 0; db < 4; ++db)
#pragma unroll
        for (int r = 0; r < 16; ++r) o[db][r] = 0.f;

    float m_ = -1e30f, l_ = 0.f;
    const int   myq   = q0 + w * 32 + c31;
    const float SCALE = 0.08838834764831845f;   // 1/sqrt(128)

    const int s_   = tid >> 2;
    const int dsub = tid & 3;
    const int vcol = PI_(s_) ^ (dsub << 4);

    const int nkt = 2 * qb + 2;
    for (int kt = 0; kt < nkt; ++kt) {
        const int k0 = kt * 64;
        __syncthreads();
#pragma unroll
        for (int it = 0; it < 4; ++it) {
            const int col = dsub * 32 + it * 8;
            const size_t goff = (size_t)(k0 + s_) * N3C + col;
            *(uint4*)&Ks[s_ * 136 + col] = *(const uint4*)(Kp + goff);
            const uint4 vv = *(const uint4*)(Vp + goff);
            const u32 vw[4] = {vv.x, vv.y, vv.z, vv.w};
#pragma unroll
            for (int j = 0; j < 8; ++j)
                Vt[(col + j) * 72 + vcol] = (u16)(vw[j >> 1] >> ((j & 1) * 16));
        }
        __syncthreads();

        f32x16 sA, sB;
#pragma unroll
        for (int r = 0; r < 16; ++r) { sA[r] = 0.f; sB[r] = 0.f; }
#pragma unroll
        for (int kc = 0; kc < 8; ++kc) {
            const bf16x8 ka = *(const bf16x8*)&Ks[c31 * 136 + kc * 16 + hi * 8];
            sA = __builtin_amdgcn_mfma_f32_32x32x16_bf16(ka, qf[kc], sA, 0, 0, 0);
            const bf16x8 kb_ = *(const bf16x8*)&Ks[(32 + c31) * 136 + kc * 16 + hi * 8];
            sB = __builtin_amdgcn_mfma_f32_32x32x16_bf16(kb_, qf[kc], sB, 0, 0, 0);
        }

        float pmax = -1e30f;
#pragma unroll
        for (int r = 0; r < 16; ++r) {
            const int cr = (r & 3) + 8 * (r >> 2) + 4 * hi;
            sA[r] = (k0 + cr      <= myq) ? sA[r] * SCALE : -1e30f;
            sB[r] = (k0 + 32 + cr <= myq) ? sB[r] * SCALE : -1e30f;
            pmax = fmaxf(pmax, fmaxf(sA[r], sB[r]));
        }
        pmax = fmaxf(pmax, __shfl_xor(pmax, 32));

        if (__any(pmax > m_ + 8.f)) {
            const float mn   = fmaxf(m_, pmax);
            const float corr = __expf(m_ - mn);
            Red[w * 32 + c31] = corr;
            float cf[16];
#pragma unroll
            for (int r = 0; r < 16; ++r)
                cf[r] = Red[w * 32 + ((r & 3) + 8 * (r >> 2) + 4 * hi)];
#pragma unroll
            for (int db = 0; db < 4; ++db)
#pragma unroll
                for (int r = 0; r < 16; ++r) o[db][r] *= cf[r];
            l_ *= corr;
            m_ = mn;
        }

        float psum = 0.f;
#pragma unroll
        for (int r = 0; r < 16; ++r) {
            sA[r] = __expf(sA[r] - m_); psum += sA[r];
            sB[r] = __expf(sB[r] - m_); psum += sB[r];
        }
        psum += __shfl_xor(psum, 32);
        l_ += psum;

#pragma unroll
        for (int kb2 = 0; kb2 < 2; ++kb2) {
#pragma unroll
            for (int c2 = 0; c2 < 2; ++c2) {
                union { u32 u[4]; bf16x8 v; } pk;
#pragma unroll
                for (int q2 = 0; q2 < 4; ++q2) {
                    const int r = 8 * c2 + 2 * q2;
                    const float e0 = kb2 ? sB[r]     : sA[r];
                    const float e1 = kb2 ? sB[r + 1] : sA[r + 1];
                    pk.u[q2] = pack2(e0, e1);
                }
#pragma unroll
                for (int db = 0; db < 4; ++db) {
                    const int colb = (kb2 * 32 + c2 * 16 + hi * 8) ^ (db << 4);
                    const bf16x8 vb = *(const bf16x8*)&Vt[(db * 32 + c31) * 72 + colb];
                    o[db] = __builtin_amdgcn_mfma_f32_32x32x16_bf16(pk.v, vb, o[db], 0, 0, 0);
                }
            }
        }
    }

    Red[w * 32 + c31] = l_;
    float lv[16];
#pragma unroll
    for (int r = 0; r < 16; ++r)
        lv[r] = 1.f / Red[w * 32 + ((r & 3) + 8 * (r >> 2) + 4 * hi)];
#pragma unroll
    for (int db = 0; db < 4; ++db)
#pragma unroll
        for (int r = 0; r < 16; ++r) {
            const int q = q0 + w * 32 + (r & 3) + 8 * (r >> 2) + 4 * hi;
            store1(y + (size_t)(b * T_ + q) * C_ + h * HD_ + db * 32 + c31,
                   o[db][r] * lv[r]);
        }
}

// ---------- launch ----------
extern "C" void kernel_launch(void* const* d_in, const int* in_sizes, int n_in,
                              void* d_out, int out_size, void* d_ws, size_t ws_size,
                              hipStream_t stream) {
    const float* x  = (const float*)d_in[0];          // [B,T,C] fp32
    // d_in[1] = causal mask (analytic) -> unused
    const float* Wa = (const float*)d_in[2];          // [3C,C] fp32
    const float* Wp = (const float*)d_in[3];          // [C,C] fp32
    float* out = (float*)d_out;                       // [B,T,C] fp32

    u16* ws = (u16*)d_ws;
    __hip_bfloat16* qkv = (__hip_bfloat16*)ws;                       // [4096,6144] bf16
    __hip_bfloat16* y   = (__hip_bfloat16*)(ws + (size_t)M_ * N3C);  // [4096,2048] bf16

    const size_t NEED = ((size_t)M_ * N3C + (size_t)M_ * C_ +        // qkv + y
                         (size_t)M_ * C_ +                           // xb
                         (size_t)N3C * C_ + (size_t)C_ * C_) * 2;    // Wab + Wpb

    if (ws_size >= NEED) {
        u16* xb  = ws + (size_t)M_ * N3C + (size_t)M_ * C_;
        u16* Wab = xb + (size_t)M_ * C_;
        u16* Wpb = Wab + (size_t)N3C * C_;

        cvt_bf16<<<(M_ * C_ / 8 + 255) / 256, 256, 0, stream>>>(x, xb, M_ * C_ / 8);
        cvt_bf16<<<(N3C * C_ / 8 + 255) / 256, 256, 0, stream>>>(Wa, Wab, N3C * C_ / 8);
        cvt_bf16<<<(C_ * C_ / 8 + 255) / 256, 256, 0, stream>>>(Wp, Wpb, C_ * C_ / 8);

        gemm_lds<__hip_bfloat16>
            <<<dim3(N3C / 128, M_ / 128), 256, 0, stream>>>(
                (const __hip_bfloat16*)xb, (const __hip_bfloat16*)Wab, qkv, N3C, C_, N3C / 128);
        rope_kernel<<<(M_ * C_) / 256, 256, 0, stream>>>(qkv);
        attn_mfma2<<<512, 256, 0, stream>>>(qkv, y);
        gemm_lds<float>
            <<<dim3(C_ / 128, M_ / 128), 256, 0, stream>>>(
                y, (const __hip_bfloat16*)Wpb, out, C_, C_, C_ / 128);
    } else {
        gemm_mfma<float, float, __hip_bfloat16>
            <<<dim3(N3C / 128, M_ / 128), 256, 0, stream>>>(x, Wa, qkv, N3C, C_, N3C / 128);
        rope_kernel<<<(M_ * C_) / 256, 256, 0, stream>>>(qkv);
        attn_mfma2<<<512, 256, 0, stream>>>(qkv, y);
        gemm_mfma<__hip_bfloat16, float, float>
            <<<dim3(C_ / 128, M_ / 128), 256, 0, stream>>>(y, Wp, out, C_, C_, C_ / 128);
    }
}

// Round 6
// 307.282 us; speedup vs baseline: 13.4549x; 1.0511x over previous
//
#include <hip/hip_runtime.h>
#include <hip/hip_bf16.h>
#include <math.h>

typedef unsigned short u16;
typedef unsigned int   u32;
typedef __attribute__((ext_vector_type(8)))  short bf16x8;   // 8 bf16 (4 VGPRs)
typedef __attribute__((ext_vector_type(4)))  float f32x4;
typedef __attribute__((ext_vector_type(16))) float f32x16;

#define B_  2
#define T_  2048
#define C_  2048
#define H_  16
#define HD_ 128
#define M_  4096          // B*T
#define N3C 6144          // 3*C

// ---------- bf16 helpers ----------
__device__ __forceinline__ float bf2f_lo(u32 u) { return __uint_as_float(u << 16); }
__device__ __forceinline__ float bf2f_hi(u32 u) { return __uint_as_float(u & 0xffff0000u); }

__device__ __forceinline__ u16 f2bf(float f) {
    u32 u = __float_as_uint(f);
    return (u16)((u + 0x7fffu + ((u >> 16) & 1u)) >> 16);   // RNE
}
__device__ __forceinline__ u32 pack2(float a, float b) {
    return (u32)f2bf(a) | ((u32)f2bf(b) << 16);
}
__device__ __forceinline__ void store1(float* p, float v) { *p = v; }
__device__ __forceinline__ void store1(__hip_bfloat16* p, float v) { *(u16*)p = f2bf(v); }

// async global->LDS, 16B per lane (wave-uniform LDS base + lane*16)
__device__ __forceinline__ void gload16(const void* g, void* l) {
    __builtin_amdgcn_global_load_lds((__attribute__((address_space(1))) void*)g,
                                     (__attribute__((address_space(3))) void*)l, 16, 0, 0);
}

// ---------- fp32 -> bf16 convert (memory-bound, 8 elems/thread) ----------
__global__ __launch_bounds__(256) void cvt_bf16(const float* __restrict__ in,
                                                u16* __restrict__ out, int n8) {
    const int i = blockIdx.x * 256 + threadIdx.x;
    if (i < n8) {
        const float4 a = ((const float4*)in)[2 * i];
        const float4 b = ((const float4*)in)[2 * i + 1];
        ((uint4*)out)[i] = make_uint4(pack2(a.x, a.y), pack2(a.z, a.w),
                                      pack2(b.x, b.y), pack2(b.z, b.w));
    }
}

// ---------- pipelined bf16 GEMM (NT): C[m,n] = sum_k A[m,k]*W[n,k] ----------
// 128x128 tile, BK=32, 4 waves; TRIPLE-buffered linear LDS; global_load_lds staging;
// ONE raw s_barrier per K-step; counted vmcnt(4) (1 tile in flight, T4).
// Race-freedom: wave passes iter-t barrier only after its t-1 ds_reads completed
// (compiler lgkmcnt before MFMAs), so staging t+2 into buf[(t+2)%3] after the
// barrier can't race t-1 readers; per-wave vmcnt(4) before the barrier ensures
// all waves' tile-t loads landed before any wave reads tile t.
template <typename TO>
__global__ __launch_bounds__(256, 3) void gemm_pipe(const __hip_bfloat16* __restrict__ A,
                                                    const __hip_bfloat16* __restrict__ W,
                                                    TO* __restrict__ Cout,
                                                    int N, int K, int gx) {
    __shared__ u16 As[3][128 * 32];
    __shared__ u16 Bs[3][128 * 32];
    const int nwg = gridDim.x * gridDim.y;
    const int id  = blockIdx.y * gx + blockIdx.x;
    const int swz = (id & 7) * (nwg >> 3) + (id >> 3);
    const int bm  = (swz / gx) * 128;
    const int bn  = (swz % gx) * 128;

    const int tid  = threadIdx.x;
    const int w    = tid >> 6;
    const int lane = tid & 63;
    const int g    = lane >> 4;       // 0..3
    const int c    = lane & 15;       // 0..15
    const int wr   = (w >> 1) * 64;
    const int wc   = (w & 1) * 64;

    // staging: wave w covers rows [w*32, w*32+32); lane l -> row +l/4, col (l&3)*8
    const int srow = lane >> 2;
    const int scol = (lane & 3) * 8;
    const __hip_bfloat16* ga0 = A + (size_t)(bm + w * 32 + srow) * K + scol;
    const __hip_bfloat16* ga1 = ga0 + (size_t)16 * K;
    const __hip_bfloat16* gb0 = W + (size_t)(bn + w * 32 + srow) * K + scol;
    const __hip_bfloat16* gb1 = gb0 + (size_t)16 * K;

#define STAGE_(bi, kk) do {                                   \
        gload16(ga0 + (kk), &As[bi][w * 1024]);               \
        gload16(ga1 + (kk), &As[bi][w * 1024 + 512]);         \
        gload16(gb0 + (kk), &Bs[bi][w * 1024]);               \
        gload16(gb1 + (kk), &Bs[bi][w * 1024 + 512]);         \
    } while (0)

    f32x4 acc[4][4];
#pragma unroll
    for (int mi = 0; mi < 4; ++mi)
#pragma unroll
        for (int ni = 0; ni < 4; ++ni)
            acc[mi][ni] = (f32x4){0.f, 0.f, 0.f, 0.f};

    const int NT = K / 32;            // >= 3
    STAGE_(0, 0);
    STAGE_(1, 32);

    int cur = 0;
    for (int t = 0; t < NT; ++t) {
        if (t + 1 < NT) { asm volatile("s_waitcnt vmcnt(4)" ::: "memory"); }
        else            { asm volatile("s_waitcnt vmcnt(0)" ::: "memory"); }
        __builtin_amdgcn_sched_barrier(0);
        __builtin_amdgcn_s_barrier();
        __builtin_amdgcn_sched_barrier(0);

        if (t + 2 < NT) {
            const int nb = (cur + 2 >= 3) ? cur - 1 : cur + 2;
            STAGE_(nb, (t + 2) * 32);
        }

        bf16x8 af[4], bfr[4];
#pragma unroll
        for (int mi = 0; mi < 4; ++mi)
            af[mi] = *(const bf16x8*)&As[cur][(wr + mi * 16 + c) * 32 + g * 8];
#pragma unroll
        for (int ni = 0; ni < 4; ++ni)
            bfr[ni] = *(const bf16x8*)&Bs[cur][(wc + ni * 16 + c) * 32 + g * 8];

        __builtin_amdgcn_s_setprio(1);
#pragma unroll
        for (int mi = 0; mi < 4; ++mi)
#pragma unroll
            for (int ni = 0; ni < 4; ++ni)
                acc[mi][ni] = __builtin_amdgcn_mfma_f32_16x16x32_bf16(
                    af[mi], bfr[ni], acc[mi][ni], 0, 0, 0);
        __builtin_amdgcn_s_setprio(0);

        cur = (cur + 1 == 3) ? 0 : cur + 1;
    }
#undef STAGE_

    // C/D layout: col = lane&15, row = 4*(lane>>4) + i   [verified m89]
#pragma unroll
    for (int mi = 0; mi < 4; ++mi)
#pragma unroll
        for (int ni = 0; ni < 4; ++ni)
#pragma unroll
            for (int i = 0; i < 4; ++i) {
                const int row = bm + wr + mi * 16 + 4 * g + i;
                const int col = bn + wc + ni * 16 + c;
                store1(Cout + (size_t)row * N + col, acc[mi][ni][i]);
            }
}

// ---------- fallback reg-staged GEMM (fp32 or bf16 sources) ----------
__device__ __forceinline__ void stage_tile(u16* dst, const float* src, int ldk, int tid) {
    const int r0  = tid >> 3;
    const int off = (tid & 7) * 4;
#pragma unroll
    for (int it = 0; it < 4; ++it) {
        const int row = r0 + it * 32;
        const float4 v = *(const float4*)(src + (size_t)row * ldk + off);
        *(uint2*)&dst[row * 40 + off] = make_uint2(pack2(v.x, v.y), pack2(v.z, v.w));
    }
}
__device__ __forceinline__ void stage_tile(u16* dst, const __hip_bfloat16* src, int ldk, int tid) {
    const int r0  = tid >> 2;
    const int off = (tid & 3) * 8;
#pragma unroll
    for (int it = 0; it < 2; ++it) {
        const int row = r0 + it * 64;
        *(uint4*)&dst[row * 40 + off] = *(const uint4*)(src + (size_t)row * ldk + off);
    }
}

template <typename TA, typename TW, typename TO>
__global__ __launch_bounds__(256) void gemm_mfma(const TA* __restrict__ A,
                                                 const TW* __restrict__ W,
                                                 TO* __restrict__ Cout,
                                                 int N, int K, int gx) {
    __shared__ u16 As[128 * 40];
    __shared__ u16 Bs[128 * 40];
    const int nwg = gridDim.x * gridDim.y;
    const int id  = blockIdx.y * gx + blockIdx.x;
    const int swz = (id & 7) * (nwg >> 3) + (id >> 3);
    const int bm  = (swz / gx) * 128;
    const int bn  = (swz % gx) * 128;

    const int tid  = threadIdx.x;
    const int w    = tid >> 6;
    const int lane = tid & 63;
    const int g    = lane >> 4;
    const int c    = lane & 15;
    const int wr   = (w >> 1) * 64;
    const int wc   = (w & 1) * 64;

    f32x4 acc[4][4];
#pragma unroll
    for (int mi = 0; mi < 4; ++mi)
#pragma unroll
        for (int ni = 0; ni < 4; ++ni)
            acc[mi][ni] = (f32x4){0.f, 0.f, 0.f, 0.f};

    const TA* Ab = A + (size_t)bm * K;
    const TW* Wb = W + (size_t)bn * K;

    for (int k0 = 0; k0 < K; k0 += 32) {
        __syncthreads();
        stage_tile(As, Ab + k0, K, tid);
        stage_tile(Bs, Wb + k0, K, tid);
        __syncthreads();

        bf16x8 af[4], bfr[4];
#pragma unroll
        for (int mi = 0; mi < 4; ++mi)
            af[mi] = *(const bf16x8*)&As[(wr + mi * 16 + c) * 40 + g * 8];
#pragma unroll
        for (int ni = 0; ni < 4; ++ni)
            bfr[ni] = *(const bf16x8*)&Bs[(wc + ni * 16 + c) * 40 + g * 8];
#pragma unroll
        for (int mi = 0; mi < 4; ++mi)
#pragma unroll
            for (int ni = 0; ni < 4; ++ni)
                acc[mi][ni] = __builtin_amdgcn_mfma_f32_16x16x32_bf16(
                    af[mi], bfr[ni], acc[mi][ni], 0, 0, 0);
    }

#pragma unroll
    for (int mi = 0; mi < 4; ++mi)
#pragma unroll
        for (int ni = 0; ni < 4; ++ni)
#pragma unroll
            for (int i = 0; i < 4; ++i) {
                const int row = bm + wr + mi * 16 + 4 * g + i;
                const int col = bn + wc + ni * 16 + c;
                store1(Cout + (size_t)row * N + col, acc[mi][ni][i]);
            }
}

// ---------- RoPE in-place on q,k thirds of qkv (bf16) ----------
__global__ __launch_bounds__(256) void rope_kernel(__hip_bfloat16* __restrict__ qkv) {
    const int id  = blockIdx.x * 256 + threadIdx.x;
    const int i   = id & 63;
    const int h   = (id >> 6) & (H_ - 1);
    const int qk  = (id >> 10) & 1;
    const int row = id >> 11;
    const int t   = row & (T_ - 1);
    const size_t base = (size_t)row * N3C + (size_t)qk * C_ + h * HD_ + 2 * i;
    u32* p = (u32*)((u16*)qkv + base);
    const u32 v = *p;
    const float x0 = bf2f_lo(v), x1 = bf2f_hi(v);
    const float l2th = 0.20762050593046f;               // log2(10000)/64
    const float theta = exp2f(-(float)i * l2th);
    const float ang = (float)t * theta;
    float s, cc;
    sincosf(ang, &s, &cc);
    *p = pack2(x0 * cc - x1 * s, x1 * cc + x0 * s);
}

// ---------- MFMA causal flash attention, 32x32 swapped-QK, T14 async-stage ----------
__device__ __forceinline__ int PI_(int s) {
    return (s & 51) | ((s & 4) << 1) | ((s & 8) >> 1);
}

__global__ __launch_bounds__(256, 2) void attn_mfma2(const __hip_bfloat16* __restrict__ qkv,
                                                     __hip_bfloat16* __restrict__ y) {
    __shared__ u16 Ks[64 * 136];
    __shared__ u16 Vt[128 * 72];
    __shared__ float Red[128];

    const int tid  = threadIdx.x;
    const int w    = tid >> 6;
    const int lane = tid & 63;
    const int c31  = lane & 31;
    const int hi   = lane >> 5;
    const int bid  = blockIdx.x;
    const int bh   = bid & 31;
    const int qb   = 15 - (bid >> 5);
    const int b    = bh >> 4, h = bh & 15;
    const int q0   = qb * 128;

    const size_t base = (size_t)b * T_ * N3C + (size_t)h * HD_;
    const __hip_bfloat16* Qp = qkv + base;
    const __hip_bfloat16* Kp = qkv + base + C_;
    const __hip_bfloat16* Vp = qkv + base + 2 * C_;

    bf16x8 qf[8];
    {
        const size_t qoff = (size_t)(q0 + w * 32 + c31) * N3C + hi * 8;
#pragma unroll
        for (int kc = 0; kc < 8; ++kc)
            qf[kc] = *(const bf16x8*)(Qp + qoff + kc * 16);
    }

    f32x16 o[4];
#pragma unroll
    for (int db = 0; db < 4; ++db)
#pragma unroll
        for (int r = 0; r < 16; ++r) o[db][r] = 0.f;

    float m_ = -1e30f, l_ = 0.f;
    const int   myq   = q0 + w * 32 + c31;
    const float SCALE = 0.08838834764831845f;   // 1/sqrt(128)

    const int s_   = tid >> 2;        // staged key row 0..63
    const int dsub = tid & 3;         // 32-col segment
    const int vcol = PI_(s_) ^ (dsub << 4);

    // T14 async stage: regs hold tile kt while tile kt+1's loads are in flight
    uint4 kreg[4], vreg[4];
#pragma unroll
    for (int it = 0; it < 4; ++it) {
        const int col = dsub * 32 + it * 8;
        const size_t goff = (size_t)s_ * N3C + col;
        kreg[it] = *(const uint4*)(Kp + goff);
        vreg[it] = *(const uint4*)(Vp + goff);
    }

    const int nkt = 2 * qb + 2;
    for (int kt = 0; kt < nkt; ++kt) {
        __syncthreads();              // previous tile's LDS reads done
        // write staged regs -> LDS (vmcnt satisfied via register dependency)
#pragma unroll
        for (int it = 0; it < 4; ++it) {
            const int col = dsub * 32 + it * 8;
            *(uint4*)&Ks[s_ * 136 + col] = kreg[it];
            const u32 vw[4] = {vreg[it].x, vreg[it].y, vreg[it].z, vreg[it].w};
#pragma unroll
            for (int j = 0; j < 8; ++j)
                Vt[(col + j) * 72 + vcol] = (u16)(vw[j >> 1] >> ((j & 1) * 16));
        }
        // issue next tile's loads (in flight across the whole compute phase)
        if (kt + 1 < nkt) {
#pragma unroll
            for (int it = 0; it < 4; ++it) {
                const int col = dsub * 32 + it * 8;
                const size_t goff = (size_t)((kt + 1) * 64 + s_) * N3C + col;
                kreg[it] = *(const uint4*)(Kp + goff);
                vreg[it] = *(const uint4*)(Vp + goff);
            }
        }
        __syncthreads();

        const int k0 = kt * 64;
        f32x16 sA, sB;
#pragma unroll
        for (int r = 0; r < 16; ++r) { sA[r] = 0.f; sB[r] = 0.f; }
        __builtin_amdgcn_s_setprio(1);
#pragma unroll
        for (int kc = 0; kc < 8; ++kc) {
            const bf16x8 ka = *(const bf16x8*)&Ks[c31 * 136 + kc * 16 + hi * 8];
            sA = __builtin_amdgcn_mfma_f32_32x32x16_bf16(ka, qf[kc], sA, 0, 0, 0);
            const bf16x8 kb_ = *(const bf16x8*)&Ks[(32 + c31) * 136 + kc * 16 + hi * 8];
            sB = __builtin_amdgcn_mfma_f32_32x32x16_bf16(kb_, qf[kc], sB, 0, 0, 0);
        }
        __builtin_amdgcn_s_setprio(0);

        float pmax = -1e30f;
#pragma unroll
        for (int r = 0; r < 16; ++r) {
            const int cr = (r & 3) + 8 * (r >> 2) + 4 * hi;
            sA[r] = (k0 + cr      <= myq) ? sA[r] * SCALE : -1e30f;
            sB[r] = (k0 + 32 + cr <= myq) ? sB[r] * SCALE : -1e30f;
            pmax = fmaxf(pmax, fmaxf(sA[r], sB[r]));
        }
        pmax = fmaxf(pmax, __shfl_xor(pmax, 32));

        if (__any(pmax > m_ + 8.f)) {           // T13 defer-max
            const float mn   = fmaxf(m_, pmax);
            const float corr = __expf(m_ - mn);
            Red[w * 32 + c31] = corr;
            float cf[16];
#pragma unroll
            for (int r = 0; r < 16; ++r)
                cf[r] = Red[w * 32 + ((r & 3) + 8 * (r >> 2) + 4 * hi)];
#pragma unroll
            for (int db = 0; db < 4; ++db)
#pragma unroll
                for (int r = 0; r < 16; ++r) o[db][r] *= cf[r];
            l_ *= corr;
            m_ = mn;
        }

        float psum = 0.f;
#pragma unroll
        for (int r = 0; r < 16; ++r) {
            sA[r] = __expf(sA[r] - m_); psum += sA[r];
            sB[r] = __expf(sB[r] - m_); psum += sB[r];
        }
        psum += __shfl_xor(psum, 32);
        l_ += psum;

        __builtin_amdgcn_s_setprio(1);
#pragma unroll
        for (int kb2 = 0; kb2 < 2; ++kb2) {
#pragma unroll
            for (int c2 = 0; c2 < 2; ++c2) {
                union { u32 u[4]; bf16x8 v; } pk;
#pragma unroll
                for (int q2 = 0; q2 < 4; ++q2) {
                    const int r = 8 * c2 + 2 * q2;
                    const float e0 = kb2 ? sB[r]     : sA[r];
                    const float e1 = kb2 ? sB[r + 1] : sA[r + 1];
                    pk.u[q2] = pack2(e0, e1);
                }
#pragma unroll
                for (int db = 0; db < 4; ++db) {
                    const int colb = (kb2 * 32 + c2 * 16 + hi * 8) ^ (db << 4);
                    const bf16x8 vb = *(const bf16x8*)&Vt[(db * 32 + c31) * 72 + colb];
                    o[db] = __builtin_amdgcn_mfma_f32_32x32x16_bf16(pk.v, vb, o[db], 0, 0, 0);
                }
            }
        }
        __builtin_amdgcn_s_setprio(0);
    }

    Red[w * 32 + c31] = l_;
    float lv[16];
#pragma unroll
    for (int r = 0; r < 16; ++r)
        lv[r] = 1.f / Red[w * 32 + ((r & 3) + 8 * (r >> 2) + 4 * hi)];
#pragma unroll
    for (int db = 0; db < 4; ++db)
#pragma unroll
        for (int r = 0; r < 16; ++r) {
            const int q = q0 + w * 32 + (r & 3) + 8 * (r >> 2) + 4 * hi;
            store1(y + (size_t)(b * T_ + q) * C_ + h * HD_ + db * 32 + c31,
                   o[db][r] * lv[r]);
        }
}

// ---------- launch ----------
extern "C" void kernel_launch(void* const* d_in, const int* in_sizes, int n_in,
                              void* d_out, int out_size, void* d_ws, size_t ws_size,
                              hipStream_t stream) {
    const float* x  = (const float*)d_in[0];          // [B,T,C] fp32
    // d_in[1] = causal mask (analytic) -> unused
    const float* Wa = (const float*)d_in[2];          // [3C,C] fp32
    const float* Wp = (const float*)d_in[3];          // [C,C] fp32
    float* out = (float*)d_out;                       // [B,T,C] fp32

    u16* ws = (u16*)d_ws;
    __hip_bfloat16* qkv = (__hip_bfloat16*)ws;                       // [4096,6144] bf16
    __hip_bfloat16* y   = (__hip_bfloat16*)(ws + (size_t)M_ * N3C);  // [4096,2048] bf16

    const size_t NEED = ((size_t)M_ * N3C + (size_t)M_ * C_ +        // qkv + y
                         (size_t)M_ * C_ +                           // xb
                         (size_t)N3C * C_ + (size_t)C_ * C_) * 2;    // Wab + Wpb

    if (ws_size >= NEED) {
        u16* xb  = ws + (size_t)M_ * N3C + (size_t)M_ * C_;
        u16* Wab = xb + (size_t)M_ * C_;
        u16* Wpb = Wab + (size_t)N3C * C_;

        cvt_bf16<<<(M_ * C_ / 8 + 255) / 256, 256, 0, stream>>>(x, xb, M_ * C_ / 8);
        cvt_bf16<<<(N3C * C_ / 8 + 255) / 256, 256, 0, stream>>>(Wa, Wab, N3C * C_ / 8);
        cvt_bf16<<<(C_ * C_ / 8 + 255) / 256, 256, 0, stream>>>(Wp, Wpb, C_ * C_ / 8);

        gemm_pipe<__hip_bfloat16>
            <<<dim3(N3C / 128, M_ / 128), 256, 0, stream>>>(
                (const __hip_bfloat16*)xb, (const __hip_bfloat16*)Wab, qkv, N3C, C_, N3C / 128);
        rope_kernel<<<(M_ * C_) / 256, 256, 0, stream>>>(qkv);
        attn_mfma2<<<512, 256, 0, stream>>>(qkv, y);
        gemm_pipe<float>
            <<<dim3(C_ / 128, M_ / 128), 256, 0, stream>>>(
                y, (const __hip_bfloat16*)Wpb, out, C_, C_, C_ / 128);
    } else {
        gemm_mfma<float, float, __hip_bfloat16>
            <<<dim3(N3C / 128, M_ / 128), 256, 0, stream>>>(x, Wa, qkv, N3C, C_, N3C / 128);
        rope_kernel<<<(M_ * C_) / 256, 256, 0, stream>>>(qkv);
        attn_mfma2<<<512, 256, 0, stream>>>(qkv, y);
        gemm_mfma<__hip_bfloat16, float, float>
            <<<dim3(C_ / 128, M_ / 128), 256, 0, stream>>>(y, Wp, out, C_, C_, C_ / 128);
    }
}